// Round 3
// baseline (486.493 us; speedup 1.0000x reference)
//
#include <hip/hip_runtime.h>
#include <math.h>

// Problem constants (fixed by the reference).
#define NUM_K   512        // codebook entries
#define DIM     64         // embedding dim (== C)
#define NROWS   131072     // 32*64*64 flattened (b,h,w) rows
#define NELEM   8388608    // NROWS*DIM
// d_out layout (float32, concatenated in return order):
// [0] loss ; [1..1+NELEM) quantized NCHW ; [1+NELEM] perplexity ;
// [2+NELEM..) codebook_indices (as float)
#define Q_OFF    1
#define PERP_OFF 8388609
#define IDX_OFF  8388610

#define KCHUNK  64         // codes staged in LDS per chunk (16 KB)

typedef float f32x2 __attribute__((ext_vector_type(2)));
typedef float f32x4 __attribute__((ext_vector_type(4)));

// ws layout: [0,4) float loss_sum ; [16,16+2048) uint counts[512] ;
//            [4096,4096+2048) float wsq[512]

// wsq[k] must be BITWISE numpy's np.sum(weight**2, axis=1):
// pairwise leaf (n=64): 8 accumulators r[j] = q[j]+q[j+8]+...+q[j+56]
// (sequential), combine ((r0+r1)+(r2+r3))+((r4+r5)+(r6+r7)).
// __fmul_rn/__fadd_rn prevent FMA contraction.  [VERIFIED round 2]
__global__ __launch_bounds__(256) void vq_wsq(const float* __restrict__ w,
                                              float* __restrict__ wsq) {
    int k = blockIdx.x * 256 + threadIdx.x;
    if (k >= NUM_K) return;
    const float* wk = w + k * DIM;
    float r[8];
#pragma unroll
    for (int j = 0; j < 8; ++j) r[j] = __fmul_rn(wk[j], wk[j]);
#pragma unroll
    for (int t = 1; t < 8; ++t)
#pragma unroll
        for (int j = 0; j < 8; ++j)
            r[j] = __fadd_rn(r[j], __fmul_rn(wk[8 * t + j], wk[8 * t + j]));
    wsq[k] = __fadd_rn(
        __fadd_rn(__fadd_rn(r[0], r[1]), __fadd_rn(r[2], r[3])),
        __fadd_rn(__fadd_rn(r[4], r[5]), __fadd_rn(r[6], r[7])));
}

// One thread per row. Score semantics FROZEN from round 2 (bitwise-verified):
//   dot_k  = sequential fmaf chain over c=0..63 (single accumulator)
//   s      = fl(fl(xsq + wsq[k]) - fl(2*dot)) ; strict < ascending k.
// This round only changes SCHEDULING: 8 independent k-chains per step
// (each chain still its own sequential fmaf sequence -> bitwise identical),
// operands fed from an LDS-transposed codebook chunk so chain pairs can form
// v_pk_fma_f32.
__global__ __launch_bounds__(256, 2) void vq_main(
        const float* __restrict__ x,      // NCHW input
        const float* __restrict__ w,      // [512,64] codebook
        const float* __restrict__ wsq,    // [512] numpy-bitwise ||w_k||^2
        float* __restrict__ out_q,        // d_out + Q_OFF (NCHW)
        float* __restrict__ out_idx,      // d_out + IDX_OFF
        float* __restrict__ loss_sum,     // ws accumulator
        unsigned* __restrict__ counts) {  // ws histogram [512]
    __shared__ float wt[KCHUNK * DIM];    // transposed chunk: wt[c][k] 16 KB
    __shared__ float swsq[NUM_K];         // 2 KB
    __shared__ unsigned hcnt[NUM_K];      // 2 KB
    __shared__ float wred[4];
    const int tid = threadIdx.x;

    for (int i = tid; i < NUM_K; i += 256) { hcnt[i] = 0; swsq[i] = wsq[i]; }

    const int n  = blockIdx.x * 256 + tid;   // flattened (b,h,w) row
    const int b  = n >> 12;
    const int hw = n & 4095;
    const float* xp = x + (size_t)b * 262144 + hw;

    // Row's 64 channel values -> registers (stride 4096 floats, coalesced).
    float xr[DIM];
#pragma unroll
    for (int c = 0; c < DIM; ++c) xr[c] = xp[(size_t)c * 4096];

    // xsq: on-grid row-constant shift; any fp32 summation works (round-2 note).
    float p0 = 0.f, p1 = 0.f, p2 = 0.f, p3 = 0.f;
#pragma unroll
    for (int c = 0; c < DIM; c += 4) {
        p0 = fmaf(xr[c + 0], xr[c + 0], p0);
        p1 = fmaf(xr[c + 1], xr[c + 1], p1);
        p2 = fmaf(xr[c + 2], xr[c + 2], p2);
        p3 = fmaf(xr[c + 3], xr[c + 3], p3);
    }
    const float xsq = __fadd_rn(__fadd_rn(p0, p1), __fadd_rn(p2, p3));

    // Staging roles: thread stages column k = tid&63 of the chunk, channel
    // block c0..c0+15 where c0 = (tid>>6)*16.
    const int sk = tid & 63;
    const int sc0 = (tid >> 6) * 16;
    const float* wsrc = w + (size_t)sk * DIM + sc0;

    float best = 3.4e38f;
    int bk = 0;

    for (int chunk = 0; chunk < NUM_K / KCHUNK; ++chunk) {
        __syncthreads();   // prev chunk consumed (also covers hcnt/swsq init)
        // Transpose-stage 64 codes: global w[kbase+sk][sc0+j] -> wt[sc0+j][sk].
        // ds_write banks: lane-varying sk -> k%32, 2 lanes/bank = free.
        {
            const float* g = wsrc + (size_t)chunk * KCHUNK * DIM;
#pragma unroll
            for (int j = 0; j < 16; j += 4) {
                float4 v = *(const float4*)(g + j);
                wt[(sc0 + j + 0) * KCHUNK + sk] = v.x;
                wt[(sc0 + j + 1) * KCHUNK + sk] = v.y;
                wt[(sc0 + j + 2) * KCHUNK + sk] = v.z;
                wt[(sc0 + j + 3) * KCHUNK + sk] = v.w;
            }
        }
        __syncthreads();

        const int kbase = chunk * KCHUNK;
        for (int kg = 0; kg < KCHUNK; kg += 8) {
            // 8 independent sequential chains (k = kbase+kg .. +7), packed
            // in f32x2 pairs -> v_pk_fma_f32. Per-half rounding == fmaf.
            f32x2 d0 = {0.f, 0.f}, d1 = {0.f, 0.f};
            f32x2 d2 = {0.f, 0.f}, d3 = {0.f, 0.f};
#pragma unroll 8
            for (int c = 0; c < DIM; ++c) {
                const float* lp = &wt[c * KCHUNK + kg];   // wave-uniform bcast
                f32x4 q0 = *(const f32x4*)lp;
                f32x4 q1 = *(const f32x4*)(lp + 4);
                f32x2 a = {xr[c], xr[c]};
                f32x2 b0 = {q0.x, q0.y}, b1 = {q0.z, q0.w};
                f32x2 b2 = {q1.x, q1.y}, b3 = {q1.z, q1.w};
#if __has_builtin(__builtin_elementwise_fma)
                d0 = __builtin_elementwise_fma(a, b0, d0);
                d1 = __builtin_elementwise_fma(a, b1, d1);
                d2 = __builtin_elementwise_fma(a, b2, d2);
                d3 = __builtin_elementwise_fma(a, b3, d3);
#else
                d0.x = fmaf(a.x, b0.x, d0.x); d0.y = fmaf(a.y, b0.y, d0.y);
                d1.x = fmaf(a.x, b1.x, d1.x); d1.y = fmaf(a.y, b1.y, d1.y);
                d2.x = fmaf(a.x, b2.x, d2.x); d2.y = fmaf(a.y, b2.y, d2.y);
                d3.x = fmaf(a.x, b3.x, d3.x); d3.y = fmaf(a.y, b3.y, d3.y);
#endif
            }
            const float dots[8] = {d0.x, d0.y, d1.x, d1.y,
                                   d2.x, d2.y, d3.x, d3.y};
#pragma unroll
            for (int j = 0; j < 8; ++j) {
                const int k = kbase + kg + j;
                float s = __fsub_rn(__fadd_rn(xsq, swsq[k]),
                                    __fmul_rn(2.0f, dots[j]));
                if (s < best) { best = s; bk = k; }  // first-min tie rule
            }
        }
    }

    atomicAdd(&hcnt[bk], 1u);

    // Epilogue: gather code row bk, write quantized (NCHW), accumulate MSE.
    float dsum = 0.f;
    const float4* wb = (const float4*)(w + (size_t)bk * DIM);
    float* oq = out_q + (size_t)b * 262144 + hw;
#pragma unroll
    for (int j = 0; j < DIM / 4; ++j) {
        float4 v = wb[j];
        float e0 = v.x - xr[4 * j + 0];
        float e1 = v.y - xr[4 * j + 1];
        float e2 = v.z - xr[4 * j + 2];
        float e3 = v.w - xr[4 * j + 3];
        dsum = fmaf(e0, e0, dsum);
        dsum = fmaf(e1, e1, dsum);
        dsum = fmaf(e2, e2, dsum);
        dsum = fmaf(e3, e3, dsum);
        oq[(size_t)(4 * j + 0) * 4096] = v.x;
        oq[(size_t)(4 * j + 1) * 4096] = v.y;
        oq[(size_t)(4 * j + 2) * 4096] = v.z;
        oq[(size_t)(4 * j + 3) * 4096] = v.w;
    }
    out_idx[n] = (float)bk;

    // Loss partial: wave shuffle reduce -> LDS -> one atomic per block.
#pragma unroll
    for (int off = 32; off > 0; off >>= 1) dsum += __shfl_down(dsum, off);
    if ((tid & 63) == 0) wred[tid >> 6] = dsum;
    __syncthreads();
    if (tid == 0)
        atomicAdd(loss_sum, (wred[0] + wred[1]) + (wred[2] + wred[3]));

    // Histogram flush: at most 2 global atomics per thread.
    for (int i = tid; i < NUM_K; i += 256) {
        unsigned c = hcnt[i];
        if (c) atomicAdd(&counts[i], c);
    }
}

__global__ __launch_bounds__(512) void vq_final(
        const unsigned* __restrict__ counts,
        const float* __restrict__ loss_sum,
        float* __restrict__ out) {
    __shared__ float red[8];
    const int tid = threadIdx.x;
    float p = (float)counts[tid] * (1.f / (float)NROWS);  // /131072 exact
    float t = p * logf(p + 1e-10f);
#pragma unroll
    for (int off = 32; off > 0; off >>= 1) t += __shfl_down(t, off);
    if ((tid & 63) == 0) red[tid >> 6] = t;
    __syncthreads();
    if (tid == 0) {
        float s = 0.f;
#pragma unroll
        for (int i = 0; i < 8; ++i) s += red[i];
        out[PERP_OFF] = expf(-s);
        // loss = q_latent + 0.25*e_latent = 1.25 * MSE (forward values equal)
        out[0] = loss_sum[0] * (1.25f / (float)NELEM);
    }
}

extern "C" void kernel_launch(void* const* d_in, const int* in_sizes, int n_in,
                              void* d_out, int out_size, void* d_ws, size_t ws_size,
                              hipStream_t stream) {
    const float* x = (const float*)d_in[0];
    const float* w = (const float*)d_in[1];
    float* out = (float*)d_out;
    char* ws = (char*)d_ws;
    float* loss_sum = (float*)ws;
    unsigned* counts = (unsigned*)(ws + 16);
    float* wsq = (float*)(ws + 4096);

    // ws is re-poisoned to 0xAA before every launch: zero accumulators.
    hipMemsetAsync(d_ws, 0, 2064, stream);

    vq_wsq<<<2, 256, 0, stream>>>(w, wsq);
    vq_main<<<NROWS / 256, 256, 0, stream>>>(x, w, wsq,
                                             out + Q_OFF, out + IDX_OFF,
                                             loss_sum, counts);
    vq_final<<<1, 512, 0, stream>>>(counts, loss_sum, out);
}

// Round 4
// 314.812 us; speedup vs baseline: 1.5453x; 1.5453x over previous
//
#include <hip/hip_runtime.h>
#include <math.h>

// Problem constants (fixed by the reference).
#define NUM_K   512        // codebook entries
#define DIM     64         // embedding dim (== C)
#define NROWS   131072     // 32*64*64 flattened (b,h,w) rows
#define NELEM   8388608    // NROWS*DIM
// d_out layout (float32, concatenated in return order):
// [0] loss ; [1..1+NELEM) quantized NCHW ; [1+NELEM] perplexity ;
// [2+NELEM..) codebook_indices (as float)
#define Q_OFF    1
#define PERP_OFF 8388609
#define IDX_OFF  8388610

// ws layout: [0,4) float loss_sum ; [16,16+2048) uint counts[512]

// One thread per row. Score semantics FROZEN (bitwise-verified round 2):
//   wsq[k]: numpy pairwise leaf n=64 (8 sequential accumulators, fixed tree)
//   dot_k : sequential single-accumulator fmaf chain over c=0..63
//   s     = fl(fl(xsq + wsq[k]) - fl(2*dot)) ; strict < , ascending k.
// Round-4 scheduling lessons:
//   - w via WAVE-UNIFORM pointers -> s_load on scalar pipe (free issue).
//     LDS-fed operands (round 3) cost more ds_read issue than they save.
//   - xr[64] MUST stay in VGPRs: (256,2)=128-reg budget, live set ~80.
//     Round-2 (VGPR=44) and round-3 (VGPR=120 + 200 MB scratch FETCH) both
//     spilled xr -> 1 scratch VMEM per fma -> 4x slowdown.
//   - 4 independent k-chains = enough ILP; 8 would blow SGPR prefetch budget.
__global__ __launch_bounds__(256, 2) void vq_main(
        const float* __restrict__ x,      // NCHW input
        const float* __restrict__ w,      // [512,64] codebook
        float* __restrict__ out_q,        // d_out + Q_OFF (NCHW)
        float* __restrict__ out_idx,      // d_out + IDX_OFF
        float* __restrict__ loss_sum,     // ws accumulator
        unsigned* __restrict__ counts) {  // ws histogram [512]
    __shared__ float swsq[NUM_K];         // 2 KB
    __shared__ unsigned hcnt[NUM_K];      // 2 KB
    __shared__ float wred[4];
    const int tid = threadIdx.x;

    const int n  = blockIdx.x * 256 + tid;   // flattened (b,h,w) row
    const int b  = n >> 12;
    const int hw = n & 4095;
    const float* xp = x + (size_t)b * 262144 + hw;

    // Row's 64 channel values -> registers (lanes coalesced per channel).
    float xr[DIM];
#pragma unroll
    for (int c = 0; c < DIM; ++c) xr[c] = xp[(size_t)c * 4096];

    // Per-block wsq into LDS — BITWISE numpy np.sum(w**2, axis=1)
    // (pairwise leaf, verified round 2). Redundant per block but ~2 us total.
    for (int kk = tid; kk < NUM_K; kk += 256) {
        const float* wk = w + kk * DIM;
        float r[8];
#pragma unroll
        for (int j = 0; j < 8; ++j) r[j] = __fmul_rn(wk[j], wk[j]);
#pragma unroll
        for (int t = 1; t < 8; ++t)
#pragma unroll
            for (int j = 0; j < 8; ++j)
                r[j] = __fadd_rn(r[j], __fmul_rn(wk[8 * t + j], wk[8 * t + j]));
        swsq[kk] = __fadd_rn(
            __fadd_rn(__fadd_rn(r[0], r[1]), __fadd_rn(r[2], r[3])),
            __fadd_rn(__fadd_rn(r[4], r[5]), __fadd_rn(r[6], r[7])));
        hcnt[kk] = 0;
    }

    // xsq: on-grid row-constant shift; low bits don't affect the argmin grid
    // (round-2 verified). Same form kept frozen anyway.
    float p0 = 0.f, p1 = 0.f, p2 = 0.f, p3 = 0.f;
#pragma unroll
    for (int c = 0; c < DIM; c += 4) {
        p0 = fmaf(xr[c + 0], xr[c + 0], p0);
        p1 = fmaf(xr[c + 1], xr[c + 1], p1);
        p2 = fmaf(xr[c + 2], xr[c + 2], p2);
        p3 = fmaf(xr[c + 3], xr[c + 3], p3);
    }
    const float xsq = __fadd_rn(__fadd_rn(p0, p1), __fadd_rn(p2, p3));

    __syncthreads();   // swsq/hcnt ready

    float best = 3.4e38f;
    int bk = 0;
    for (int k = 0; k < NUM_K; k += 4) {
        // 4 independent sequential chains; w pointers wave-uniform -> s_load.
        const float* w0 = w + (size_t)k * DIM;
        const float* w1 = w0 + DIM;
        const float* w2 = w0 + 2 * DIM;
        const float* w3 = w0 + 3 * DIM;
        float d0 = 0.f, d1 = 0.f, d2 = 0.f, d3 = 0.f;
#pragma unroll
        for (int c = 0; c < DIM; ++c) {
            d0 = fmaf(xr[c], w0[c], d0);
            d1 = fmaf(xr[c], w1[c], d1);
            d2 = fmaf(xr[c], w2[c], d2);
            d3 = fmaf(xr[c], w3[c], d3);
        }
        float4 wq = *(const float4*)&swsq[k];   // one ds_read_b128
        float s0 = __fsub_rn(__fadd_rn(xsq, wq.x), __fmul_rn(2.0f, d0));
        float s1 = __fsub_rn(__fadd_rn(xsq, wq.y), __fmul_rn(2.0f, d1));
        float s2 = __fsub_rn(__fadd_rn(xsq, wq.z), __fmul_rn(2.0f, d2));
        float s3 = __fsub_rn(__fadd_rn(xsq, wq.w), __fmul_rn(2.0f, d3));
        // strict < in ascending k = np.argmin first-occurrence tie rule
        if (s0 < best) { best = s0; bk = k; }
        if (s1 < best) { best = s1; bk = k + 1; }
        if (s2 < best) { best = s2; bk = k + 2; }
        if (s3 < best) { best = s3; bk = k + 3; }
    }

    atomicAdd(&hcnt[bk], 1u);

    // Epilogue: gather code row bk, write quantized (NCHW), accumulate MSE.
    float dsum = 0.f;
    const float4* wb = (const float4*)(w + (size_t)bk * DIM);
    float* oq = out_q + (size_t)b * 262144 + hw;
#pragma unroll
    for (int j = 0; j < DIM / 4; ++j) {
        float4 v = wb[j];
        float e0 = v.x - xr[4 * j + 0];
        float e1 = v.y - xr[4 * j + 1];
        float e2 = v.z - xr[4 * j + 2];
        float e3 = v.w - xr[4 * j + 3];
        dsum = fmaf(e0, e0, dsum);
        dsum = fmaf(e1, e1, dsum);
        dsum = fmaf(e2, e2, dsum);
        dsum = fmaf(e3, e3, dsum);
        oq[(size_t)(4 * j + 0) * 4096] = v.x;
        oq[(size_t)(4 * j + 1) * 4096] = v.y;
        oq[(size_t)(4 * j + 2) * 4096] = v.z;
        oq[(size_t)(4 * j + 3) * 4096] = v.w;
    }
    out_idx[n] = (float)bk;

    // Loss partial: wave shuffle reduce -> LDS -> one atomic per block.
#pragma unroll
    for (int off = 32; off > 0; off >>= 1) dsum += __shfl_down(dsum, off);
    if ((tid & 63) == 0) wred[tid >> 6] = dsum;
    __syncthreads();
    if (tid == 0)
        atomicAdd(loss_sum, (wred[0] + wred[1]) + (wred[2] + wred[3]));

    // Histogram flush: at most 2 global atomics per thread.
    for (int i = tid; i < NUM_K; i += 256) {
        unsigned c = hcnt[i];
        if (c) atomicAdd(&counts[i], c);
    }
}

__global__ __launch_bounds__(512) void vq_final(
        const unsigned* __restrict__ counts,
        const float* __restrict__ loss_sum,
        float* __restrict__ out) {
    __shared__ float red[8];
    const int tid = threadIdx.x;
    float p = (float)counts[tid] * (1.f / (float)NROWS);  // /131072 exact
    float t = p * logf(p + 1e-10f);
#pragma unroll
    for (int off = 32; off > 0; off >>= 1) t += __shfl_down(t, off);
    if ((tid & 63) == 0) red[tid >> 6] = t;
    __syncthreads();
    if (tid == 0) {
        float s = 0.f;
#pragma unroll
        for (int i = 0; i < 8; ++i) s += red[i];
        out[PERP_OFF] = expf(-s);
        // loss = q_latent + 0.25*e_latent = 1.25 * MSE (forward values equal)
        out[0] = loss_sum[0] * (1.25f / (float)NELEM);
    }
}

extern "C" void kernel_launch(void* const* d_in, const int* in_sizes, int n_in,
                              void* d_out, int out_size, void* d_ws, size_t ws_size,
                              hipStream_t stream) {
    const float* x = (const float*)d_in[0];
    const float* w = (const float*)d_in[1];
    float* out = (float*)d_out;
    char* ws = (char*)d_ws;
    float* loss_sum = (float*)ws;
    unsigned* counts = (unsigned*)(ws + 16);

    // ws is re-poisoned to 0xAA before every launch: zero accumulators.
    hipMemsetAsync(d_ws, 0, 2064, stream);

    vq_main<<<NROWS / 256, 256, 0, stream>>>(x, w,
                                             out + Q_OFF, out + IDX_OFF,
                                             loss_sum, counts);
    vq_final<<<1, 512, 0, stream>>>(counts, loss_sum, out);
}

// Round 5
// 271.998 us; speedup vs baseline: 1.7886x; 1.1574x over previous
//
#include <hip/hip_runtime.h>
#include <math.h>

// Problem constants (fixed by the reference).
#define NUM_K   512        // codebook entries
#define DIM     64         // embedding dim (== C)
#define NROWS   131072     // 32*64*64 flattened (b,h,w) rows
#define NELEM   8388608    // NROWS*DIM
// d_out layout (float32, concatenated in return order):
// [0] loss ; [1..1+NELEM) quantized NCHW ; [1+NELEM] perplexity ;
// [2+NELEM..) codebook_indices (as float)
#define Q_OFF    1
#define PERP_OFF 8388609
#define IDX_OFF  8388610

typedef float f32x2 __attribute__((ext_vector_type(2)));

// ws layout: [0,4) float loss_sum ; [16,16+2048) uint counts[512] ;
//            [8192, 8192+131072) float wt[64][512] (transposed codebook)

// wt[c][k] = w[k][c]; writes coalesced (k fastest), 128 KB total, ~2 us.
__global__ __launch_bounds__(256) void vq_transpose(const float* __restrict__ w,
                                                    float* __restrict__ wt) {
    int idx = blockIdx.x * 256 + threadIdx.x;   // 32768 elems
    int c = idx >> 9, k = idx & 511;
    wt[idx] = w[k * DIM + c];
}

// One thread per row. Score semantics FROZEN (bitwise-verified round 2):
//   wsq[k]: numpy pairwise leaf n=64 (8 sequential accumulators, fixed tree)
//   dot_k : sequential single-accumulator fma chain over c=0..63
//   s     = fl(fl(xsq + wsq[k]) - fl(2*dot)) ; strict < , ascending k.
// Round-5 scheduling: x row lives in LDS (xs[c][tid], conflict-free b32) so
// NO large register array exists to spill (rounds 2-4 all lost xr[64]).
// w comes from a pre-transposed global wt[c][k] via wave-uniform pointers
// (s_load, free scalar pipe); adjacent-k pairs feed v_pk_fma_f32 — per-half
// IEEE fma, so each k-chain stays bitwise identical to the frozen fmaf chain.
__global__ __launch_bounds__(256, 2) void vq_main(
        const float* __restrict__ x,      // NCHW input
        const float* __restrict__ w,      // [512,64] codebook (row-major)
        const float* __restrict__ wt,     // [64,512] transposed codebook
        float* __restrict__ out_q,        // d_out + Q_OFF (NCHW)
        float* __restrict__ out_idx,      // d_out + IDX_OFF
        float* __restrict__ loss_sum,     // ws accumulator
        unsigned* __restrict__ counts) {  // ws histogram [512]
    __shared__ float xs[DIM * 256];       // xs[c][tid], 64 KB
    __shared__ float swsq[NUM_K];         // 2 KB
    __shared__ unsigned hcnt[NUM_K];      // 2 KB
    __shared__ float wred[4];
    const int tid = threadIdx.x;

    const int n  = blockIdx.x * 256 + tid;   // flattened (b,h,w) row
    const int b  = n >> 12;
    const int hw = n & 4095;
    const float* xp = x + (size_t)b * 262144 + hw;

    // Stage x row into LDS (writes conflict-free: banks tid%32, 2/bank) and
    // compute frozen-form xsq on the fly.
    float p0 = 0.f, p1 = 0.f, p2 = 0.f, p3 = 0.f;
#pragma unroll
    for (int c = 0; c < DIM; c += 4) {
        float v0 = xp[(size_t)(c + 0) * 4096];
        float v1 = xp[(size_t)(c + 1) * 4096];
        float v2 = xp[(size_t)(c + 2) * 4096];
        float v3 = xp[(size_t)(c + 3) * 4096];
        xs[(c + 0) * 256 + tid] = v0;
        xs[(c + 1) * 256 + tid] = v1;
        xs[(c + 2) * 256 + tid] = v2;
        xs[(c + 3) * 256 + tid] = v3;
        p0 = fmaf(v0, v0, p0);
        p1 = fmaf(v1, v1, p1);
        p2 = fmaf(v2, v2, p2);
        p3 = fmaf(v3, v3, p3);
    }
    const float xsq = __fadd_rn(__fadd_rn(p0, p1), __fadd_rn(p2, p3));

    // Per-block wsq into LDS — BITWISE numpy np.sum(w**2, axis=1)
    // (pairwise leaf, verified round 2).
    for (int kk = tid; kk < NUM_K; kk += 256) {
        const float* wk = w + kk * DIM;
        float r[8];
#pragma unroll
        for (int j = 0; j < 8; ++j) r[j] = __fmul_rn(wk[j], wk[j]);
#pragma unroll
        for (int t = 1; t < 8; ++t)
#pragma unroll
            for (int j = 0; j < 8; ++j)
                r[j] = __fadd_rn(r[j], __fmul_rn(wk[8 * t + j], wk[8 * t + j]));
        swsq[kk] = __fadd_rn(
            __fadd_rn(__fadd_rn(r[0], r[1]), __fadd_rn(r[2], r[3])),
            __fadd_rn(__fadd_rn(r[4], r[5]), __fadd_rn(r[6], r[7])));
        hcnt[kk] = 0;
    }
    __syncthreads();   // xs/swsq/hcnt ready

    float best = 3.4e38f;
    int bk = 0;
#pragma unroll 1
    for (int kg = 0; kg < NUM_K; kg += 16) {
        // 16 independent frozen chains as 8 pk-pairs.
        f32x2 acc[8];
#pragma unroll
        for (int i = 0; i < 8; ++i) acc[i] = (f32x2){0.f, 0.f};
#pragma unroll 4
        for (int c = 0; c < DIM; ++c) {
            float xc = xs[c * 256 + tid];             // ds_read_b32, no conflict
            f32x2 xx = {xc, xc};
            const f32x2* wp = (const f32x2*)(wt + c * NUM_K + kg);  // uniform
#pragma unroll
            for (int i = 0; i < 8; ++i)
                acc[i] = __builtin_elementwise_fma(xx, wp[i], acc[i]);
        }
#pragma unroll
        for (int j = 0; j < 16; ++j) {
            float d = (j & 1) ? acc[j >> 1].y : acc[j >> 1].x;
            float s = __fsub_rn(__fadd_rn(xsq, swsq[kg + j]),
                                __fmul_rn(2.0f, d));
            if (s < best) { best = s; bk = kg + j; }  // first-min tie rule
        }
    }

    atomicAdd(&hcnt[bk], 1u);

    // Epilogue: gather code row bk, write quantized (NCHW), accumulate MSE.
    float dsum = 0.f;
    const float4* wb = (const float4*)(w + (size_t)bk * DIM);
    float* oq = out_q + (size_t)b * 262144 + hw;
#pragma unroll
    for (int j = 0; j < DIM / 4; ++j) {
        float4 v = wb[j];
        float e0 = v.x - xs[(4 * j + 0) * 256 + tid];
        float e1 = v.y - xs[(4 * j + 1) * 256 + tid];
        float e2 = v.z - xs[(4 * j + 2) * 256 + tid];
        float e3 = v.w - xs[(4 * j + 3) * 256 + tid];
        dsum = fmaf(e0, e0, dsum);
        dsum = fmaf(e1, e1, dsum);
        dsum = fmaf(e2, e2, dsum);
        dsum = fmaf(e3, e3, dsum);
        oq[(size_t)(4 * j + 0) * 4096] = v.x;
        oq[(size_t)(4 * j + 1) * 4096] = v.y;
        oq[(size_t)(4 * j + 2) * 4096] = v.z;
        oq[(size_t)(4 * j + 3) * 4096] = v.w;
    }
    out_idx[n] = (float)bk;

    // Loss partial: wave shuffle reduce -> LDS -> one atomic per block.
#pragma unroll
    for (int off = 32; off > 0; off >>= 1) dsum += __shfl_down(dsum, off);
    if ((tid & 63) == 0) wred[tid >> 6] = dsum;
    __syncthreads();
    if (tid == 0)
        atomicAdd(loss_sum, (wred[0] + wred[1]) + (wred[2] + wred[3]));

    // Histogram flush: at most 2 global atomics per thread.
    for (int i = tid; i < NUM_K; i += 256) {
        unsigned c = hcnt[i];
        if (c) atomicAdd(&counts[i], c);
    }
}

__global__ __launch_bounds__(512) void vq_final(
        const unsigned* __restrict__ counts,
        const float* __restrict__ loss_sum,
        float* __restrict__ out) {
    __shared__ float red[8];
    const int tid = threadIdx.x;
    float p = (float)counts[tid] * (1.f / (float)NROWS);  // /131072 exact
    float t = p * logf(p + 1e-10f);
#pragma unroll
    for (int off = 32; off > 0; off >>= 1) t += __shfl_down(t, off);
    if ((tid & 63) == 0) red[tid >> 6] = t;
    __syncthreads();
    if (tid == 0) {
        float s = 0.f;
#pragma unroll
        for (int i = 0; i < 8; ++i) s += red[i];
        out[PERP_OFF] = expf(-s);
        // loss = q_latent + 0.25*e_latent = 1.25 * MSE (forward values equal)
        out[0] = loss_sum[0] * (1.25f / (float)NELEM);
    }
}

extern "C" void kernel_launch(void* const* d_in, const int* in_sizes, int n_in,
                              void* d_out, int out_size, void* d_ws, size_t ws_size,
                              hipStream_t stream) {
    const float* x = (const float*)d_in[0];
    const float* w = (const float*)d_in[1];
    float* out = (float*)d_out;
    char* ws = (char*)d_ws;
    float* loss_sum = (float*)ws;
    unsigned* counts = (unsigned*)(ws + 16);
    float* wt = (float*)(ws + 8192);   // 128 KB transposed codebook

    // ws is re-poisoned to 0xAA before every launch: zero accumulators.
    hipMemsetAsync(d_ws, 0, 2064, stream);

    vq_transpose<<<128, 256, 0, stream>>>(w, wt);
    vq_main<<<NROWS / 256, 256, 0, stream>>>(x, w, wt,
                                             out + Q_OFF, out + IDX_OFF,
                                             loss_sum, counts);
    vq_final<<<1, 512, 0, stream>>>(counts, loss_sum, out);
}